// Round 6
// baseline (1620.405 us; speedup 1.0000x reference)
//
#include <hip/hip_runtime.h>
#include <cfloat>

#define BB 64
#define NPERB 2048
#define KNN 16
#define NTOT (BB*NPERB)
#define MCAND 24

// numpy pairwise_sum (scalar 8-accumulator path) of x_f^2 over 64 contiguous fp32
__device__ __forceinline__ float np_sq64(const float* __restrict__ xs) {
    float r[8];
#pragma unroll
    for (int j = 0; j < 8; ++j) r[j] = __fmul_rn(xs[j], xs[j]);
#pragma unroll
    for (int i = 1; i < 8; ++i)
#pragma unroll
        for (int j = 0; j < 8; ++j)
            r[j] = __fadd_rn(r[j], __fmul_rn(xs[8*i + j], xs[8*i + j]));
    float t01 = __fadd_rn(r[0], r[1]);
    float t23 = __fadd_rn(r[2], r[3]);
    float t45 = __fadd_rn(r[4], r[5]);
    float t67 = __fadd_rn(r[6], r[7]);
    return __fadd_rn(__fadd_rn(t01, t23), __fadd_rn(t45, t67));
}

// Kernel 1: A[n,o] = x_n.(W1-W2)[o] + bias[o];  Bv[n,o] = x_n.W2[o];  sqnp[n] = numpy-order |x_n|^2
__global__ __launch_bounds__(256) void k_transform(const float* __restrict__ x,
    const float* __restrict__ w, const float* __restrict__ bias,
    float* __restrict__ Ap, float* __restrict__ Bvv, float* __restrict__ sqnp)
{
    __shared__ float w1m[64*64];   // [f][o] = W[o][f] - W[o][64+f]
    __shared__ float w2t[64*64];   // [f][o] = W[o][64+f]
    __shared__ float xs[128*64];
    int t = threadIdx.x;
    int r0 = blockIdx.x * 128;
#pragma unroll
    for (int i = 0; i < 16; ++i) {
        int e = t + i*256; int f = e >> 6; int o = e & 63;
        float w2 = w[o*128 + 64 + f];
        float w1 = w[o*128 + f];
        w2t[f*64 + o] = w2;
        w1m[f*64 + o] = w1 - w2;
    }
#pragma unroll
    for (int i = 0; i < 32; ++i) { int idx = t + i*256; xs[idx] = x[(size_t)r0*64 + idx]; }
    __syncthreads();
    int o = t & 63;
    float br = bias[o];
    for (int g = 0; g < 32; ++g) {
        int rl = g*4 + (t >> 6);
        float a1 = 0.f, a2 = 0.f;
#pragma unroll
        for (int f = 0; f < 64; ++f) {
            float xv = xs[rl*64 + f];
            a1 += xv * w1m[f*64 + o];
            a2 += xv * w2t[f*64 + o];
        }
        int row = r0 + rl;
        Ap[(size_t)row*64 + o] = a1 + br;
        Bvv[(size_t)row*64 + o] = a2;
        if (o == 0) sqnp[row] = np_sq64(&xs[rl*64]);
    }
}

// Kernel 2: fast fp32 scan -> top-24 candidates; reference-order fp32 rescore -> top-16 (ties -> lower idx)
__global__ __launch_bounds__(256) void k_topk(const float4* __restrict__ x4,
    const float* __restrict__ sq, int* __restrict__ nbr)
{
    __shared__ float4 xc4[128*16];   // 128 cols x 64 floats
    __shared__ float sqs[128];
    int t = threadIdx.x;
    int bi = blockIdx.x;
    int row = bi*256 + t;
    int rb = (bi >> 3) << 11;        // batch row base
    float4 xr[16];
    // stage this block's own 256 rows through LDS (coalesced), copy own row to regs
    for (int h = 0; h < 2; ++h) {
        int base = (bi*256 + h*128) * 16;
#pragma unroll
        for (int i = 0; i < 8; ++i) { int idx = t + i*256; xc4[idx] = x4[base + idx]; }
        __syncthreads();
        if ((t >> 7) == h) {
            int rl = t & 127;
#pragma unroll
            for (int fc = 0; fc < 16; ++fc) xr[fc] = xc4[rl*16 + fc];
        }
        __syncthreads();
    }
    float sqr = sq[row];
    float key[MCAND]; int kidx[MCAND];
#pragma unroll
    for (int j = 0; j < MCAND; ++j) { key[j] = FLT_MAX; kidx[j] = 0; }

    for (int ch = 0; ch < 16; ++ch) {
        int cb = ch * 128;
        int gbase = (rb + cb) * 16;
#pragma unroll
        for (int i = 0; i < 8; ++i) { int idx = t + i*256; xc4[idx] = x4[gbase + idx]; }
        if (t < 128) sqs[t] = sq[rb + cb + t];
        __syncthreads();
        for (int c = 0; c < 128; ++c) {
            float s0 = 0.f, s1 = 0.f, s2 = 0.f, s3 = 0.f;
#pragma unroll
            for (int fc = 0; fc < 16; ++fc) {
                float4 xc = xc4[c*16 + fc];
                s0 += xr[fc].x * xc.x; s1 += xr[fc].y * xc.y;
                s2 += xr[fc].z * xc.z; s3 += xr[fc].w * xc.w;
            }
            float dot = (s0 + s1) + (s2 + s3);
            float kk = (sqr + sqs[c]) - 2.f * dot;
            if (kk < key[MCAND-1]) {
                int ci = cb + c;
#pragma unroll
                for (int j = MCAND-1; j >= 1; --j) {
                    bool sh = key[j-1] > kk;
                    bool pl = (!sh) && (key[j] > kk);
                    float nk = sh ? key[j-1] : (pl ? kk : key[j]);
                    int   ni = sh ? kidx[j-1] : (pl ? ci : kidx[j]);
                    key[j] = nk; kidx[j] = ni;
                }
                if (key[0] > kk) { key[0] = kk; kidx[0] = ci; }
            }
        }
        __syncthreads();
    }

    // Rescore: BLAS/matmul-style dot — sequential forward FMA chain, single fp32 accumulator
    // (OpenBLAS sgemm / Eigen gebp micro-kernels vectorize over m/n; k accumulates
    //  sequentially with fused FMA: c = fma(a_k, b_k, c), k = 0..63 ascending.)
    float dk[KNN]; int di[KNN];
#pragma unroll
    for (int j = 0; j < KNN; ++j) { dk[j] = FLT_MAX; di[j] = 0x7fffffff; }
    for (int m = 0; m < MCAND; ++m) {
        int c = kidx[m];
        const float4* xb4 = &x4[(size_t)(rb + c) * 16];
        float dot = 0.f;
#pragma unroll
        for (int i = 0; i < 16; ++i) {
            float4 a = xr[i];
            float4 b = xb4[i];
            dot = fmaf(a.x, b.x, dot);
            dot = fmaf(a.y, b.y, dot);
            dot = fmaf(a.z, b.z, dot);
            dot = fmaf(a.w, b.w, dot);
        }
        float kd = __fsub_rn(__fadd_rn(sqr, sq[rb + c]), __fmul_rn(2.0f, dot));
        bool better = (kd < dk[KNN-1]) || (kd == dk[KNN-1] && c < di[KNN-1]);
        if (better) {
#pragma unroll
            for (int j = KNN-1; j >= 1; --j) {
                bool sh = (dk[j-1] > kd) || (dk[j-1] == kd && di[j-1] > c);
                bool pl = (!sh) && ((dk[j] > kd) || (dk[j] == kd && di[j] > c));
                float nk = sh ? dk[j-1] : (pl ? kd : dk[j]);
                int   ni = sh ? di[j-1] : (pl ? c  : di[j]);
                dk[j] = nk; di[j] = ni;
            }
            if ((dk[0] > kd) || (dk[0] == kd && di[0] > c)) { dk[0] = kd; di[0] = c; }
        }
    }
#pragma unroll
    for (int k = 0; k < KNN; ++k) nbr[(size_t)row*16 + k] = di[k];
}

// Kernel 3: out[n,o] = relu(A[n,o] + max_k Bv[nbr_k, o])
__global__ __launch_bounds__(256) void k_combine(const float* __restrict__ Ap,
    const float* __restrict__ Bvv, const int* __restrict__ nbr, float* __restrict__ out)
{
    int t = threadIdx.x;
    int row = blockIdx.x*4 + (t >> 6);
    int o = t & 63;
    int rb = (row >> 11) << 11;
    float m = -FLT_MAX;
#pragma unroll
    for (int k = 0; k < 16; ++k) {
        int c = nbr[(size_t)row*16 + k];
        m = fmaxf(m, Bvv[(size_t)(rb + c)*64 + o]);
    }
    out[(size_t)row*64 + o] = fmaxf(Ap[(size_t)row*64 + o] + m, 0.f);
}

extern "C" void kernel_launch(void* const* d_in, const int* in_sizes, int n_in,
                              void* d_out, int out_size, void* d_ws, size_t ws_size,
                              hipStream_t stream) {
    const float* x    = (const float*)d_in[0];
    // d_in[1] = batch (contiguous per batch; unused)
    const float* w    = (const float*)d_in[2];
    const float* bias = (const float*)d_in[3];
    float* out = (float*)d_out;

    float* Ap   = (float*)d_ws;
    float* Bvv  = Ap  + (size_t)NTOT * 64;
    float* sqnp = Bvv + (size_t)NTOT * 64;
    int*   nbr  = (int*)(sqnp + NTOT);

    k_transform<<<1024, 256, 0, stream>>>(x, w, bias, Ap, Bvv, sqnp);
    k_topk<<<512, 256, 0, stream>>>((const float4*)x, sqnp, nbr);
    k_combine<<<NTOT/4, 256, 0, stream>>>(Ap, Bvv, nbr, out);
}

// Round 7
// 1038.264 us; speedup vs baseline: 1.5607x; 1.5607x over previous
//
#include <hip/hip_runtime.h>
#include <cfloat>

#define BB 64
#define NPERB 2048
#define KNN 16
#define NTOT (BB*NPERB)
#define MC 20

typedef __bf16 bf16x8 __attribute__((ext_vector_type(8)));
typedef float  f32x4  __attribute__((ext_vector_type(4)));

// numpy pairwise_sum (scalar 8-accumulator path) of x_f^2 over 64 contiguous fp32
__device__ __forceinline__ float np_sq64(const float* __restrict__ xs) {
    float r[8];
#pragma unroll
    for (int j = 0; j < 8; ++j) r[j] = __fmul_rn(xs[j], xs[j]);
#pragma unroll
    for (int i = 1; i < 8; ++i)
#pragma unroll
        for (int j = 0; j < 8; ++j)
            r[j] = __fadd_rn(r[j], __fmul_rn(xs[8*i + j], xs[8*i + j]));
    float t01 = __fadd_rn(r[0], r[1]);
    float t23 = __fadd_rn(r[2], r[3]);
    float t45 = __fadd_rn(r[4], r[5]);
    float t67 = __fadd_rn(r[6], r[7]);
    return __fadd_rn(__fadd_rn(t01, t23), __fadd_rn(t45, t67));
}

__device__ __forceinline__ unsigned short bf16rn(float f) {
    unsigned int u = __float_as_uint(f);
    u += 0x7fffu + ((u >> 16) & 1u);
    return (unsigned short)(u >> 16);
}
__device__ __forceinline__ unsigned int pk2(float a, float b) {
    return ((unsigned int)bf16rn(b) << 16) | (unsigned int)bf16rn(a);
}
// monotone fp32->uint key, truncated to 21 bits, col idx in low 11 bits (ties -> lower idx)
__device__ __forceinline__ unsigned int packkey(float s, int c) {
    unsigned int u = __float_as_uint(s);
    u = (u & 0x80000000u) ? ~u : (u | 0x80000000u);
    return (u & 0xFFFFF800u) | (unsigned int)c;
}

// Kernel 1: A[n,o] = x_n.(W1-W2)[o] + bias[o];  Bv[n,o] = x_n.W2[o];  sqnp[n] = numpy-order |x_n|^2
__global__ __launch_bounds__(256) void k_transform(const float* __restrict__ x,
    const float* __restrict__ w, const float* __restrict__ bias,
    float* __restrict__ Ap, float* __restrict__ Bvv, float* __restrict__ sqnp)
{
    __shared__ float w1m[64*64];
    __shared__ float w2t[64*64];
    __shared__ float xs[128*64];
    int t = threadIdx.x;
    int r0 = blockIdx.x * 128;
#pragma unroll
    for (int i = 0; i < 16; ++i) {
        int e = t + i*256; int f = e >> 6; int o = e & 63;
        float w2 = w[o*128 + 64 + f];
        float w1 = w[o*128 + f];
        w2t[f*64 + o] = w2;
        w1m[f*64 + o] = w1 - w2;
    }
#pragma unroll
    for (int i = 0; i < 32; ++i) { int idx = t + i*256; xs[idx] = x[(size_t)r0*64 + idx]; }
    __syncthreads();
    int o = t & 63;
    float br = bias[o];
    for (int g = 0; g < 32; ++g) {
        int rl = g*4 + (t >> 6);
        float a1 = 0.f, a2 = 0.f;
#pragma unroll
        for (int f = 0; f < 64; ++f) {
            float xv = xs[rl*64 + f];
            a1 += xv * w1m[f*64 + o];
            a2 += xv * w2t[f*64 + o];
        }
        int row = r0 + rl;
        Ap[(size_t)row*64 + o] = a1 + br;
        Bvv[(size_t)row*64 + o] = a2;
        if (o == 0) sqnp[row] = np_sq64(&xs[rl*64]);
    }
}

// Kernel 2: bf16 MFMA Gram scores -> per-half-row top-20 filter (packed uint keys)
//           -> np-exact fp32 rescore of 40 candidates -> exact top-16 (ties -> lower idx)
__global__ __launch_bounds__(256) void k_topk(const float4* __restrict__ x4,
    const float* __restrict__ sq, int* __restrict__ nbr)
{
    __shared__ __align__(16) unsigned short bsh[64*72];   // col tile, bf16, row stride 72
    __shared__ __align__(16) float scores[64*132];        // col-major scores[c][r]; overlaid: A-staging, cand lists
    __shared__ float sqr_sh[128];
    __shared__ float sqc_sh[64];

    int t = threadIdx.x;
    int lane = t & 63;
    int w = t >> 6;
    int batch = blockIdx.x >> 4;
    int strip = blockIdx.x & 15;
    int rbase = batch * 2048;
    int r0g = rbase + strip * 128;
    int ln = lane & 15, qd = lane >> 4;

    // ---- stage this block's 128 rows as bf16 into scores-overlay ----
    unsigned short* ash = (unsigned short*)scores;
#pragma unroll
    for (int i = 0; i < 8; ++i) {
        int chunk = t + i*256;                 // 0..2047
        int p = chunk >> 4, qq = chunk & 15;
        float4 g = x4[(size_t)(r0g + p)*16 + qq];
        uint2 v; v.x = pk2(g.x, g.y); v.y = pk2(g.z, g.w);
        *(uint2*)&ash[p*72 + qq*4] = v;
    }
    if (t < 128) sqr_sh[t] = sq[r0g + t];
    __syncthreads();

    // A-fragments: A[m=lane&15][k=quad*8+j]; rows w*32..w*32+31, kept in regs all kernel
    bf16x8 afr[2][2];
#pragma unroll
    for (int rt = 0; rt < 2; ++rt)
#pragma unroll
        for (int kc = 0; kc < 2; ++kc)
            afr[rt][kc] = *(const bf16x8*)&ash[(w*32 + rt*16 + ln)*72 + kc*32 + qd*8];
    __syncthreads();   // scores region now free

    unsigned int ks[MC];
#pragma unroll
    for (int j = 0; j < MC; ++j) ks[j] = 0xFFFFFFFFu;
    int selr = t & 127, selh = t >> 7;

    for (int ct = 0; ct < 32; ++ct) {
        int cb = ct * 64;
        // stage B col-tile (64 points) as bf16
#pragma unroll
        for (int i = 0; i < 4; ++i) {
            int chunk = t + i*256;             // 0..1023
            int p = chunk >> 4, qq = chunk & 15;
            float4 g = x4[(size_t)(rbase + cb + p)*16 + qq];
            uint2 v; v.x = pk2(g.x, g.y); v.y = pk2(g.z, g.w);
            *(uint2*)&bsh[p*72 + qq*4] = v;
        }
        if (t < 64) sqc_sh[t] = sq[rbase + cb + t];
        __syncthreads();

        // MFMA: wave w computes rows [w*32, w*32+32) x 64 cols; scores -> LDS col-major
#pragma unroll
        for (int ct2 = 0; ct2 < 4; ++ct2) {
            bf16x8 b0 = *(const bf16x8*)&bsh[(ct2*16 + ln)*72 + qd*8];
            bf16x8 b1 = *(const bf16x8*)&bsh[(ct2*16 + ln)*72 + 32 + qd*8];
            int C = ct2*16 + ln;
            float sc = sqc_sh[C];
#pragma unroll
            for (int rt = 0; rt < 2; ++rt) {
                f32x4 acc = {0.f, 0.f, 0.f, 0.f};
                acc = __builtin_amdgcn_mfma_f32_16x16x32_bf16(afr[rt][0], b0, acc, 0, 0, 0);
                acc = __builtin_amdgcn_mfma_f32_16x16x32_bf16(afr[rt][1], b1, acc, 0, 0, 0);
                int Rb = w*32 + rt*16 + qd*4;   // C/D: col=lane&15, row=quad*4+reg (m89-verified)
                f32x4 v;
                v[0] = sqr_sh[Rb+0] + sc - 2.f*acc[0];
                v[1] = sqr_sh[Rb+1] + sc - 2.f*acc[1];
                v[2] = sqr_sh[Rb+2] + sc - 2.f*acc[2];
                v[3] = sqr_sh[Rb+3] + sc - 2.f*acc[3];
                *(f32x4*)&scores[C*132 + Rb] = v;
            }
        }
        __syncthreads();

        // filter: thread = (row, half); tiered min/max cascade on packed keys
#pragma unroll 4
        for (int i = 0; i < 32; ++i) {
            int c = selh*32 + i;
            float s = scores[c*132 + selr];
            unsigned int u = packkey(s, cb + c);
            if (u < ks[MC-1]) {
                if (u >= ks[15]) {
#pragma unroll
                    for (int j = 16; j < MC; ++j) { unsigned int lo = min(ks[j], u); u = max(ks[j], u); ks[j] = lo; }
                } else if (u >= ks[7]) {
#pragma unroll
                    for (int j = 8; j < MC; ++j) { unsigned int lo = min(ks[j], u); u = max(ks[j], u); ks[j] = lo; }
                } else {
#pragma unroll
                    for (int j = 0; j < MC; ++j) { unsigned int lo = min(ks[j], u); u = max(ks[j], u); ks[j] = lo; }
                }
            }
        }
        __syncthreads();
    }

    // dump candidate indices, then np-exact rescore (one thread per row)
    unsigned int* cand = (unsigned int*)scores;      // 128 rows x 40 idx
#pragma unroll
    for (int j = 0; j < MC; ++j) cand[selr*40 + selh*20 + j] = ks[j] & 0x7FFu;
    __syncthreads();

    if (t < 128) {
        int r = t;
        float4 xr[16];
#pragma unroll
        for (int i = 0; i < 16; ++i) xr[i] = x4[(size_t)(r0g + r)*16 + i];
        float sqr = sqr_sh[r];
        float dk[KNN]; int di[KNN];
#pragma unroll
        for (int j = 0; j < KNN; ++j) { dk[j] = FLT_MAX; di[j] = 0x7fffffff; }
        for (int m = 0; m < 2*MC; ++m) {
            int c = (int)cand[r*40 + m];
            const float4* xb4 = &x4[(size_t)(rbase + c)*16];
            float dot = 0.f;   // reference-order: sequential forward FMA chain
#pragma unroll
            for (int i = 0; i < 16; ++i) {
                float4 a = xr[i]; float4 b = xb4[i];
                dot = fmaf(a.x, b.x, dot);
                dot = fmaf(a.y, b.y, dot);
                dot = fmaf(a.z, b.z, dot);
                dot = fmaf(a.w, b.w, dot);
            }
            float kd = __fsub_rn(__fadd_rn(sqr, sq[rbase + c]), __fmul_rn(2.0f, dot));
            bool better = (kd < dk[KNN-1]) || (kd == dk[KNN-1] && c < di[KNN-1]);
            if (better) {
#pragma unroll
                for (int j = KNN-1; j >= 1; --j) {
                    bool sh = (dk[j-1] > kd) || (dk[j-1] == kd && di[j-1] > c);
                    bool pl = (!sh) && ((dk[j] > kd) || (dk[j] == kd && di[j] > c));
                    float nk = sh ? dk[j-1] : (pl ? kd : dk[j]);
                    int ni = sh ? di[j-1] : (pl ? c : di[j]);
                    dk[j] = nk; di[j] = ni;
                }
                if ((dk[0] > kd) || (dk[0] == kd && di[0] > c)) { dk[0] = kd; di[0] = c; }
            }
        }
#pragma unroll
        for (int k = 0; k < KNN; ++k) nbr[(size_t)(r0g + r)*16 + k] = di[k];
    }
}

// Kernel 3: out[n,o] = relu(A[n,o] + max_k Bv[nbr_k, o])
__global__ __launch_bounds__(256) void k_combine(const float* __restrict__ Ap,
    const float* __restrict__ Bvv, const int* __restrict__ nbr, float* __restrict__ out)
{
    int t = threadIdx.x;
    int row = blockIdx.x*4 + (t >> 6);
    int o = t & 63;
    int rb = (row >> 11) << 11;
    float m = -FLT_MAX;
#pragma unroll
    for (int k = 0; k < 16; ++k) {
        int c = nbr[(size_t)row*16 + k];
        m = fmaxf(m, Bvv[(size_t)(rb + c)*64 + o]);
    }
    out[(size_t)row*64 + o] = fmaxf(Ap[(size_t)row*64 + o] + m, 0.f);
}

extern "C" void kernel_launch(void* const* d_in, const int* in_sizes, int n_in,
                              void* d_out, int out_size, void* d_ws, size_t ws_size,
                              hipStream_t stream) {
    const float* x    = (const float*)d_in[0];
    // d_in[1] = batch (contiguous per batch; unused)
    const float* w    = (const float*)d_in[2];
    const float* bias = (const float*)d_in[3];
    float* out = (float*)d_out;

    float* Ap   = (float*)d_ws;
    float* Bvv  = Ap  + (size_t)NTOT * 64;
    float* sqnp = Bvv + (size_t)NTOT * 64;
    int*   nbr  = (int*)(sqnp + NTOT);

    k_transform<<<1024, 256, 0, stream>>>(x, w, bias, Ap, Bvv, sqnp);
    k_topk<<<1024, 256, 0, stream>>>((const float4*)x, sqnp, nbr);
    k_combine<<<NTOT/4, 256, 0, stream>>>(Ap, Bvv, nbr, out);
}

// Round 8
// 933.602 us; speedup vs baseline: 1.7356x; 1.1121x over previous
//
#include <hip/hip_runtime.h>
#include <cfloat>

#define BB 64
#define NPERB 2048
#define KNN 16
#define NTOT (BB*NPERB)
#define NCAND 24

typedef __bf16 bf16x8 __attribute__((ext_vector_type(8)));
typedef float  f32x4  __attribute__((ext_vector_type(4)));

// numpy pairwise_sum (scalar 8-accumulator path) of x_f^2 over 64 contiguous fp32
__device__ __forceinline__ float np_sq64(const float* __restrict__ xs) {
    float r[8];
#pragma unroll
    for (int j = 0; j < 8; ++j) r[j] = __fmul_rn(xs[j], xs[j]);
#pragma unroll
    for (int i = 1; i < 8; ++i)
#pragma unroll
        for (int j = 0; j < 8; ++j)
            r[j] = __fadd_rn(r[j], __fmul_rn(xs[8*i + j], xs[8*i + j]));
    float t01 = __fadd_rn(r[0], r[1]);
    float t23 = __fadd_rn(r[2], r[3]);
    float t45 = __fadd_rn(r[4], r[5]);
    float t67 = __fadd_rn(r[6], r[7]);
    return __fadd_rn(__fadd_rn(t01, t23), __fadd_rn(t45, t67));
}

__device__ __forceinline__ unsigned short bf16rn(float f) {
    unsigned int u = __float_as_uint(f);
    u += 0x7fffu + ((u >> 16) & 1u);
    return (unsigned short)(u >> 16);
}
__device__ __forceinline__ unsigned int pk2(float a, float b) {
    return ((unsigned int)bf16rn(b) << 16) | (unsigned int)bf16rn(a);
}
// monotone fp32->uint key truncated to 21 bits, col idx in low 11 bits (ties -> lower idx)
__device__ __forceinline__ unsigned int packkey(float s, int c) {
    unsigned int u = __float_as_uint(s);
    u = (u & 0x80000000u) ? ~u : (u | 0x80000000u);
    return (u & 0xFFFFF800u) | (unsigned int)c;
}

// Kernel 1: A[n,o] = x_n.(W1-W2)[o] + bias[o];  Bv[n,o] = x_n.W2[o];  sqnp[n] = numpy-order |x_n|^2
__global__ __launch_bounds__(256) void k_transform(const float* __restrict__ x,
    const float* __restrict__ w, const float* __restrict__ bias,
    float* __restrict__ Ap, float* __restrict__ Bvv, float* __restrict__ sqnp)
{
    __shared__ float w1m[64*64];
    __shared__ float w2t[64*64];
    __shared__ float xs[128*64];
    int t = threadIdx.x;
    int r0 = blockIdx.x * 128;
#pragma unroll
    for (int i = 0; i < 16; ++i) {
        int e = t + i*256; int f = e >> 6; int o = e & 63;
        float w2 = w[o*128 + 64 + f];
        float w1 = w[o*128 + f];
        w2t[f*64 + o] = w2;
        w1m[f*64 + o] = w1 - w2;
    }
#pragma unroll
    for (int i = 0; i < 32; ++i) { int idx = t + i*256; xs[idx] = x[(size_t)r0*64 + idx]; }
    __syncthreads();
    int o = t & 63;
    float br = bias[o];
    for (int g = 0; g < 32; ++g) {
        int rl = g*4 + (t >> 6);
        float a1 = 0.f, a2 = 0.f;
#pragma unroll
        for (int f = 0; f < 64; ++f) {
            float xv = xs[rl*64 + f];
            a1 += xv * w1m[f*64 + o];
            a2 += xv * w2t[f*64 + o];
        }
        int row = r0 + rl;
        Ap[(size_t)row*64 + o] = a1 + br;
        Bvv[(size_t)row*64 + o] = a2;
        if (o == 0) sqnp[row] = np_sq64(&xs[rl*64]);
    }
}

// Kernel 2 (rewritten): transposed bf16 MFMA -> in-register divergence-free flat-16 filter
// (4 lanes per row, cols mod-16 quartered) -> per-row merge to bf16-top-24 -> np-exact
// rescore -> exact top-16 (ties -> lower idx).
__global__ __launch_bounds__(256) void k_topk(const float4* __restrict__ x4,
    const float* __restrict__ sq, int* __restrict__ nbr)
{
    __shared__ __align__(16) unsigned short bsh[64*72];   // col-tile bf16, stride 72
    __shared__ __align__(16) unsigned short rsh[64*72];   // this block's 64 rows bf16
    __shared__ float sqc_sh[64];
    __shared__ __align__(16) unsigned int cand[64*68];    // 64 keys/row; later (kd,idx) dump
    __shared__ unsigned short cand24[64*NCAND];

    int t = threadIdx.x;
    int lane = t & 63;
    int w = t >> 6;
    int ln = lane & 15, qd = lane >> 4;
    int batch = blockIdx.x >> 5;
    int strip = blockIdx.x & 31;
    int rbase = batch * NPERB;
    int r0g = rbase + strip * 64;

    // stage the block's 64 rows as bf16
#pragma unroll
    for (int i = 0; i < 4; ++i) {
        int ch = t + i*256; int p = ch >> 4; int q = ch & 15;
        float4 g = x4[(size_t)(r0g + p)*16 + q];
        uint2 v; v.x = pk2(g.x, g.y); v.y = pk2(g.z, g.w);
        *(uint2*)&rsh[p*72 + q*4] = v;
    }
    __syncthreads();
    // row fragments: B-operand, n = ln -> row w*16+ln, k = qd*8+j (+32)
    bf16x8 rf0 = *(const bf16x8*)&rsh[(w*16 + ln)*72 + qd*8];
    bf16x8 rf1 = *(const bf16x8*)&rsh[(w*16 + ln)*72 + 32 + qd*8];

    unsigned int ks[16];
#pragma unroll
    for (int j = 0; j < 16; ++j) ks[j] = 0xFFFFFFFFu;

    for (int ct = 0; ct < 32; ++ct) {
        int cb = ct * 64;
#pragma unroll
        for (int i = 0; i < 4; ++i) {
            int ch = t + i*256; int p = ch >> 4; int q = ch & 15;
            float4 g = x4[(size_t)(rbase + cb + p)*16 + q];
            uint2 v; v.x = pk2(g.x, g.y); v.y = pk2(g.z, g.w);
            *(uint2*)&bsh[p*72 + q*4] = v;
        }
        if (t < 64) sqc_sh[t] = sq[rbase + cb + t];
        __syncthreads();

#pragma unroll
        for (int ct2 = 0; ct2 < 4; ++ct2) {
            int pt = ct2*16 + ln;
            bf16x8 a0 = *(const bf16x8*)&bsh[pt*72 + qd*8];
            bf16x8 a1 = *(const bf16x8*)&bsh[pt*72 + 32 + qd*8];
            f32x4 acc = {0.f, 0.f, 0.f, 0.f};
            acc = __builtin_amdgcn_mfma_f32_16x16x32_bf16(a0, rf0, acc, 0, 0, 0);
            acc = __builtin_amdgcn_mfma_f32_16x16x32_bf16(a1, rf1, acc, 0, 0, 0);
            // acc[j]: score for row (w*16+ln), col (cb + ct2*16 + qd*4 + j)
            f32x4 sc4 = *(const f32x4*)&sqc_sh[ct2*16 + qd*4];
#pragma unroll
            for (int j = 0; j < 4; ++j) {
                float s = fmaf(-2.f, acc[j], sc4[j]);   // per-row const sqr dropped (monotone)
                unsigned int u = packkey(s, cb + ct2*16 + qd*4 + j);
                // branchless flat 16-deep ascending cascade
#pragma unroll
                for (int jj = 0; jj < 16; ++jj) {
                    unsigned int lo = min(ks[jj], u);
                    u = max(ks[jj], u);
                    ks[jj] = lo;
                }
            }
        }
        __syncthreads();
    }

    // dump per-lane keys: row = w*16+ln, quarter qd
    {
        int r = w*16 + ln;
#pragma unroll
        for (int j = 0; j < 16; ++j) cand[r*68 + qd*16 + j] = ks[j];
    }
    __syncthreads();

    // merge: thread r < 64 -> bf16-top-24 of the row's 64 keys -> cand24 (cols)
    if (t < 64) {
        unsigned int m24[NCAND];
#pragma unroll
        for (int j = 0; j < NCAND; ++j) m24[j] = 0xFFFFFFFFu;
        for (int i = 0; i < 64; ++i) {
            unsigned int u = cand[t*68 + i];
#pragma unroll
            for (int jj = 0; jj < NCAND; ++jj) {
                unsigned int lo = min(m24[jj], u);
                u = max(m24[jj], u);
                m24[jj] = lo;
            }
        }
#pragma unroll
        for (int j = 0; j < NCAND; ++j) cand24[t*NCAND + j] = (unsigned short)(m24[j] & 0x7FFu);
    }
    __syncthreads();

    // rescore: thread = (row = t&63, group = t>>6), 6 candidates each; np-exact chain (R6-verified)
    {
        int r = t & 63, grp = t >> 6;
        float sqr = sq[r0g + r];
        float4 xrA[8];
#pragma unroll
        for (int i = 0; i < 8; ++i) xrA[i] = x4[(size_t)(r0g + r)*16 + i];
        float* kdf = (float*)cand;
#pragma unroll
        for (int m6 = 0; m6 < 6; ++m6) {
            int m = grp*6 + m6;
            int c = (int)cand24[r*NCAND + m];
            const float4* xb4 = &x4[(size_t)(rbase + c)*16];
            float dot = 0.f;
#pragma unroll
            for (int i = 0; i < 8; ++i) {
                float4 a = xrA[i]; float4 b = xb4[i];
                dot = fmaf(a.x, b.x, dot); dot = fmaf(a.y, b.y, dot);
                dot = fmaf(a.z, b.z, dot); dot = fmaf(a.w, b.w, dot);
            }
#pragma unroll
            for (int i = 8; i < 16; ++i) {
                float4 a = x4[(size_t)(r0g + r)*16 + i]; float4 b = xb4[i];
                dot = fmaf(a.x, b.x, dot); dot = fmaf(a.y, b.y, dot);
                dot = fmaf(a.z, b.z, dot); dot = fmaf(a.w, b.w, dot);
            }
            float kd = __fsub_rn(__fadd_rn(sqr, sq[rbase + c]), __fmul_rn(2.0f, dot));
            kdf[r*68 + m] = kd;
            cand[r*68 + 32 + m] = (unsigned int)c;
        }
    }
    __syncthreads();

    // final exact top-16 with (key, idx) ordering; write nbr
    if (t < 64) {
        float* kdf = (float*)cand;
        float dk[KNN]; int di[KNN];
#pragma unroll
        for (int j = 0; j < KNN; ++j) { dk[j] = FLT_MAX; di[j] = 0x7fffffff; }
        for (int m = 0; m < NCAND; ++m) {
            float kd = kdf[t*68 + m];
            int c = (int)cand[t*68 + 32 + m];
            bool better = (kd < dk[KNN-1]) || (kd == dk[KNN-1] && c < di[KNN-1]);
            if (better) {
#pragma unroll
                for (int j = KNN-1; j >= 1; --j) {
                    bool sh = (dk[j-1] > kd) || (dk[j-1] == kd && di[j-1] > c);
                    bool pl = (!sh) && ((dk[j] > kd) || (dk[j] == kd && di[j] > c));
                    float nk = sh ? dk[j-1] : (pl ? kd : dk[j]);
                    int ni = sh ? di[j-1] : (pl ? c : di[j]);
                    dk[j] = nk; di[j] = ni;
                }
                if ((dk[0] > kd) || (dk[0] == kd && di[0] > c)) { dk[0] = kd; di[0] = c; }
            }
        }
#pragma unroll
        for (int k = 0; k < KNN; ++k) nbr[(size_t)(r0g + t)*16 + k] = di[k];
    }
}

// Kernel 3: out[n,o] = relu(A[n,o] + max_k Bv[nbr_k, o])
__global__ __launch_bounds__(256) void k_combine(const float* __restrict__ Ap,
    const float* __restrict__ Bvv, const int* __restrict__ nbr, float* __restrict__ out)
{
    int t = threadIdx.x;
    int row = blockIdx.x*4 + (t >> 6);
    int o = t & 63;
    int rb = (row >> 11) << 11;
    float m = -FLT_MAX;
#pragma unroll
    for (int k = 0; k < 16; ++k) {
        int c = nbr[(size_t)row*16 + k];
        m = fmaxf(m, Bvv[(size_t)(rb + c)*64 + o]);
    }
    out[(size_t)row*64 + o] = fmaxf(Ap[(size_t)row*64 + o] + m, 0.f);
}

extern "C" void kernel_launch(void* const* d_in, const int* in_sizes, int n_in,
                              void* d_out, int out_size, void* d_ws, size_t ws_size,
                              hipStream_t stream) {
    const float* x    = (const float*)d_in[0];
    // d_in[1] = batch (contiguous per batch; unused)
    const float* w    = (const float*)d_in[2];
    const float* bias = (const float*)d_in[3];
    float* out = (float*)d_out;

    float* Ap   = (float*)d_ws;
    float* Bvv  = Ap  + (size_t)NTOT * 64;
    float* sqnp = Bvv + (size_t)NTOT * 64;
    int*   nbr  = (int*)(sqnp + NTOT);

    k_transform<<<1024, 256, 0, stream>>>(x, w, bias, Ap, Bvv, sqnp);
    k_topk<<<2048, 256, 0, stream>>>((const float4*)x, sqnp, nbr);
    k_combine<<<NTOT/4, 256, 0, stream>>>(Ap, Bvv, nbr, out);
}

// Round 9
// 821.818 us; speedup vs baseline: 1.9717x; 1.1360x over previous
//
#include <hip/hip_runtime.h>
#include <cfloat>

#define BB 64
#define NPERB 2048
#define KNN 16
#define NTOT (BB*NPERB)
#define NCAND 24

typedef __bf16 bf16x8 __attribute__((ext_vector_type(8)));
typedef float  f32x4  __attribute__((ext_vector_type(4)));

__device__ __forceinline__ unsigned int med3u(unsigned int a, unsigned int b, unsigned int c) {
    unsigned int d;
    asm("v_med3_u32 %0, %1, %2, %3" : "=v"(d) : "v"(a), "v"(b), "v"(c));
    return d;
}

// numpy pairwise_sum (scalar 8-accumulator path) of x_f^2 over 64 contiguous fp32
__device__ __forceinline__ float np_sq64(const float* __restrict__ xs) {
    float r[8];
#pragma unroll
    for (int j = 0; j < 8; ++j) r[j] = __fmul_rn(xs[j], xs[j]);
#pragma unroll
    for (int i = 1; i < 8; ++i)
#pragma unroll
        for (int j = 0; j < 8; ++j)
            r[j] = __fadd_rn(r[j], __fmul_rn(xs[8*i + j], xs[8*i + j]));
    float t01 = __fadd_rn(r[0], r[1]);
    float t23 = __fadd_rn(r[2], r[3]);
    float t45 = __fadd_rn(r[4], r[5]);
    float t67 = __fadd_rn(r[6], r[7]);
    return __fadd_rn(__fadd_rn(t01, t23), __fadd_rn(t45, t67));
}

__device__ __forceinline__ unsigned short bf16rn(float f) {
    unsigned int u = __float_as_uint(f);
    u += 0x7fffu + ((u >> 16) & 1u);
    return (unsigned short)(u >> 16);
}
__device__ __forceinline__ unsigned int pk2(float a, float b) {
    return ((unsigned int)bf16rn(b) << 16) | (unsigned int)bf16rn(a);
}

// Kernel 1: A[n,o] = x_n.(W1-W2)[o] + bias[o];  Bv[n,o] = x_n.W2[o];  sqnp[n] = numpy-order |x_n|^2
__global__ __launch_bounds__(256) void k_transform(const float* __restrict__ x,
    const float* __restrict__ w, const float* __restrict__ bias,
    float* __restrict__ Ap, float* __restrict__ Bvv, float* __restrict__ sqnp)
{
    __shared__ float w1m[64*64];
    __shared__ float w2t[64*64];
    __shared__ float xs[128*64];
    int t = threadIdx.x;
    int r0 = blockIdx.x * 128;
#pragma unroll
    for (int i = 0; i < 16; ++i) {
        int e = t + i*256; int f = e >> 6; int o = e & 63;
        float w2 = w[o*128 + 64 + f];
        float w1 = w[o*128 + f];
        w2t[f*64 + o] = w2;
        w1m[f*64 + o] = w1 - w2;
    }
#pragma unroll
    for (int i = 0; i < 32; ++i) { int idx = t + i*256; xs[idx] = x[(size_t)r0*64 + idx]; }
    __syncthreads();
    int o = t & 63;
    float br = bias[o];
    for (int g = 0; g < 32; ++g) {
        int rl = g*4 + (t >> 6);
        float a1 = 0.f, a2 = 0.f;
#pragma unroll
        for (int f = 0; f < 64; ++f) {
            float xv = xs[rl*64 + f];
            a1 += xv * w1m[f*64 + o];
            a2 += xv * w2t[f*64 + o];
        }
        int row = r0 + rl;
        Ap[(size_t)row*64 + o] = a1 + br;
        Bvv[(size_t)row*64 + o] = a2;
        if (o == 0) sqnp[row] = np_sq64(&xs[rl*64]);
    }
}

// Kernel 2: transposed bf16 MFMA -> in-register med3 flat-16 filter (4 lanes per row)
//           -> per-row merge to bf16-top-24 -> np-exact rescore -> exact top-16.
__global__ __launch_bounds__(256) void k_topk(const float4* __restrict__ x4,
    const float* __restrict__ sq, int* __restrict__ nbr)
{
    // LDS overlay: phase1 {bsh 9216 | rsh 9216 | sqc 256}; phase2 {cand 17408 | cand24 3072}
    __shared__ __align__(16) char smem[20480];
    unsigned short* bsh = (unsigned short*)smem;             // col-tile bf16, stride 72
    unsigned short* rsh = (unsigned short*)(smem + 9216);    // block's 64 rows bf16
    float* sqc_sh       = (float*)(smem + 18432);
    unsigned int* cand  = (unsigned int*)smem;               // 64 rows x 68
    unsigned short* cand24 = (unsigned short*)(smem + 17408);

    int t = threadIdx.x;
    int lane = t & 63;
    int w = t >> 6;
    int ln = lane & 15, qd = lane >> 4;
    int batch = blockIdx.x >> 5;
    int strip = blockIdx.x & 31;
    int rbase = batch * NPERB;
    int r0g = rbase + strip * 64;

    // stage the block's 64 rows as bf16
#pragma unroll
    for (int i = 0; i < 4; ++i) {
        int ch = t + i*256; int p = ch >> 4; int q = ch & 15;
        float4 g = x4[(size_t)(r0g + p)*16 + q];
        uint2 v; v.x = pk2(g.x, g.y); v.y = pk2(g.z, g.w);
        *(uint2*)&rsh[p*72 + q*4] = v;
    }
    __syncthreads();
    // row fragments: B-operand, n = ln -> row w*16+ln, k = qd*8+j (+32)
    bf16x8 rf0 = *(const bf16x8*)&rsh[(w*16 + ln)*72 + qd*8];
    bf16x8 rf1 = *(const bf16x8*)&rsh[(w*16 + ln)*72 + 32 + qd*8];
    float sqr16 = sq[r0g + w*16 + ln] + 16.f;   // row const; +16 keeps scores positive

    unsigned int ks[16];
#pragma unroll
    for (int j = 0; j < 16; ++j) ks[j] = 0xFFFFFFFFu;

    for (int ct = 0; ct < 32; ++ct) {
        int cb = ct * 64;
#pragma unroll
        for (int i = 0; i < 4; ++i) {
            int ch = t + i*256; int p = ch >> 4; int q = ch & 15;
            float4 g = x4[(size_t)(rbase + cb + p)*16 + q];
            uint2 v; v.x = pk2(g.x, g.y); v.y = pk2(g.z, g.w);
            *(uint2*)&bsh[p*72 + q*4] = v;
        }
        if (t < 64) sqc_sh[t] = sq[rbase + cb + t];
        __syncthreads();

#pragma unroll
        for (int ct2 = 0; ct2 < 4; ++ct2) {
            int pt = ct2*16 + ln;
            bf16x8 a0 = *(const bf16x8*)&bsh[pt*72 + qd*8];
            bf16x8 a1 = *(const bf16x8*)&bsh[pt*72 + 32 + qd*8];
            f32x4 acc = {0.f, 0.f, 0.f, 0.f};
            acc = __builtin_amdgcn_mfma_f32_16x16x32_bf16(a0, rf0, acc, 0, 0, 0);
            acc = __builtin_amdgcn_mfma_f32_16x16x32_bf16(a1, rf1, acc, 0, 0, 0);
            // acc[j]: score for row (w*16+ln), col (cb + ct2*16 + qd*4 + j)
            f32x4 sc4 = *(const f32x4*)&sqc_sh[ct2*16 + qd*4];
            int idxb = cb + ct2*16 + qd*4;
#pragma unroll
            for (int j = 0; j < 4; ++j) {
                float s = fmaf(-2.f, acc[j], sc4[j] + sqr16);   // > 0 always
                unsigned int u = (__float_as_uint(s) & 0xFFFFF800u) | (unsigned int)(idxb + j);
                // med3 sorted-insert: depth-1, 16 independent ops
#pragma unroll
                for (int jj = 15; jj >= 1; --jj) ks[jj] = med3u(u, ks[jj-1], ks[jj]);
                ks[0] = min(ks[0], u);
            }
        }
        __syncthreads();
    }

    // dump per-lane keys: row = w*16+ln, quarter qd
    {
        int r = w*16 + ln;
#pragma unroll
        for (int j = 0; j < 16; ++j) cand[r*68 + qd*16 + j] = ks[j];
    }
    __syncthreads();

    // merge: thread r < 64 -> bf16-top-24 of the row's 64 keys -> cand24 (cols)
    if (t < 64) {
        unsigned int m24[NCAND];
#pragma unroll
        for (int j = 0; j < NCAND; ++j) m24[j] = 0xFFFFFFFFu;
        for (int i = 0; i < 64; ++i) {
            unsigned int u = cand[t*68 + i];
#pragma unroll
            for (int jj = NCAND-1; jj >= 1; --jj) m24[jj] = med3u(u, m24[jj-1], m24[jj]);
            m24[0] = min(m24[0], u);
        }
#pragma unroll
        for (int j = 0; j < NCAND; ++j) cand24[t*NCAND + j] = (unsigned short)(m24[j] & 0x7FFu);
    }
    __syncthreads();

    // rescore: thread = (row = t&63, group = t>>6), 6 candidates each; np-exact chain (R6-verified)
    {
        int r = t & 63, grp = t >> 6;
        float sqr = sq[r0g + r];
        float4 xrA[8];
#pragma unroll
        for (int i = 0; i < 8; ++i) xrA[i] = x4[(size_t)(r0g + r)*16 + i];
        float* kdf = (float*)cand;
#pragma unroll
        for (int m6 = 0; m6 < 6; ++m6) {
            int m = grp*6 + m6;
            int c = (int)cand24[r*NCAND + m];
            const float4* xb4 = &x4[(size_t)(rbase + c)*16];
            float dot = 0.f;
#pragma unroll
            for (int i = 0; i < 8; ++i) {
                float4 a = xrA[i]; float4 b = xb4[i];
                dot = fmaf(a.x, b.x, dot); dot = fmaf(a.y, b.y, dot);
                dot = fmaf(a.z, b.z, dot); dot = fmaf(a.w, b.w, dot);
            }
#pragma unroll
            for (int i = 8; i < 16; ++i) {
                float4 a = x4[(size_t)(r0g + r)*16 + i]; float4 b = xb4[i];
                dot = fmaf(a.x, b.x, dot); dot = fmaf(a.y, b.y, dot);
                dot = fmaf(a.z, b.z, dot); dot = fmaf(a.w, b.w, dot);
            }
            float kd = __fsub_rn(__fadd_rn(sqr, sq[rbase + c]), __fmul_rn(2.0f, dot));
            kdf[r*68 + m] = kd;
            cand[r*68 + 32 + m] = (unsigned int)c;
        }
    }
    __syncthreads();

    // final exact top-16 with (key, idx) ordering; write nbr
    if (t < 64) {
        float* kdf = (float*)cand;
        float dk[KNN]; int di[KNN];
#pragma unroll
        for (int j = 0; j < KNN; ++j) { dk[j] = FLT_MAX; di[j] = 0x7fffffff; }
        for (int m = 0; m < NCAND; ++m) {
            float kd = kdf[t*68 + m];
            int c = (int)cand[t*68 + 32 + m];
            bool better = (kd < dk[KNN-1]) || (kd == dk[KNN-1] && c < di[KNN-1]);
            if (better) {
#pragma unroll
                for (int j = KNN-1; j >= 1; --j) {
                    bool sh = (dk[j-1] > kd) || (dk[j-1] == kd && di[j-1] > c);
                    bool pl = (!sh) && ((dk[j] > kd) || (dk[j] == kd && di[j] > c));
                    float nk = sh ? dk[j-1] : (pl ? kd : dk[j]);
                    int ni = sh ? di[j-1] : (pl ? c : di[j]);
                    dk[j] = nk; di[j] = ni;
                }
                if ((dk[0] > kd) || (dk[0] == kd && di[0] > c)) { dk[0] = kd; di[0] = c; }
            }
        }
#pragma unroll
        for (int k = 0; k < KNN; ++k) nbr[(size_t)(r0g + t)*16 + k] = di[k];
    }
}

// Kernel 3: out[n,o] = relu(A[n,o] + max_k Bv[nbr_k, o])
__global__ __launch_bounds__(256) void k_combine(const float* __restrict__ Ap,
    const float* __restrict__ Bvv, const int* __restrict__ nbr, float* __restrict__ out)
{
    int t = threadIdx.x;
    int row = blockIdx.x*4 + (t >> 6);
    int o = t & 63;
    int rb = (row >> 11) << 11;
    float m = -FLT_MAX;
#pragma unroll
    for (int k = 0; k < 16; ++k) {
        int c = nbr[(size_t)row*16 + k];
        m = fmaxf(m, Bvv[(size_t)(rb + c)*64 + o]);
    }
    out[(size_t)row*64 + o] = fmaxf(Ap[(size_t)row*64 + o] + m, 0.f);
}

extern "C" void kernel_launch(void* const* d_in, const int* in_sizes, int n_in,
                              void* d_out, int out_size, void* d_ws, size_t ws_size,
                              hipStream_t stream) {
    const float* x    = (const float*)d_in[0];
    // d_in[1] = batch (contiguous per batch; unused)
    const float* w    = (const float*)d_in[2];
    const float* bias = (const float*)d_in[3];
    float* out = (float*)d_out;

    float* Ap   = (float*)d_ws;
    float* Bvv  = Ap  + (size_t)NTOT * 64;
    float* sqnp = Bvv + (size_t)NTOT * 64;
    int*   nbr  = (int*)(sqnp + NTOT);

    k_transform<<<1024, 256, 0, stream>>>(x, w, bias, Ap, Bvv, sqnp);
    k_topk<<<2048, 256, 0, stream>>>((const float4*)x, sqnp, nbr);
    k_combine<<<NTOT/4, 256, 0, stream>>>(Ap, Bvv, nbr, out);
}

// Round 10
// 636.670 us; speedup vs baseline: 2.5451x; 1.2908x over previous
//
#include <hip/hip_runtime.h>
#include <cfloat>

#define BB 64
#define NPERB 2048
#define KNN 16
#define NTOT (BB*NPERB)
#define NCAND 24

typedef __bf16 bf16x8 __attribute__((ext_vector_type(8)));
typedef float  f32x4  __attribute__((ext_vector_type(4)));

__device__ __forceinline__ unsigned int med3u(unsigned int a, unsigned int b, unsigned int c) {
    unsigned int d;
    asm("v_med3_u32 %0, %1, %2, %3" : "=v"(d) : "v"(a), "v"(b), "v"(c));
    return d;
}

// numpy pairwise_sum (scalar 8-accumulator path) of x_f^2 over 64 contiguous fp32
__device__ __forceinline__ float np_sq64(const float* __restrict__ xs) {
    float r[8];
#pragma unroll
    for (int j = 0; j < 8; ++j) r[j] = __fmul_rn(xs[j], xs[j]);
#pragma unroll
    for (int i = 1; i < 8; ++i)
#pragma unroll
        for (int j = 0; j < 8; ++j)
            r[j] = __fadd_rn(r[j], __fmul_rn(xs[8*i + j], xs[8*i + j]));
    float t01 = __fadd_rn(r[0], r[1]);
    float t23 = __fadd_rn(r[2], r[3]);
    float t45 = __fadd_rn(r[4], r[5]);
    float t67 = __fadd_rn(r[6], r[7]);
    return __fadd_rn(__fadd_rn(t01, t23), __fadd_rn(t45, t67));
}

__device__ __forceinline__ unsigned short bf16rn(float f) {
    unsigned int u = __float_as_uint(f);
    u += 0x7fffu + ((u >> 16) & 1u);
    return (unsigned short)(u >> 16);
}
__device__ __forceinline__ unsigned int pk2(float a, float b) {
    return ((unsigned int)bf16rn(b) << 16) | (unsigned int)bf16rn(a);
}

// Kernel 1: A -> out (in place for k3), Bv, numpy-order sq, and bf16 copy of x
__global__ __launch_bounds__(256) void k_transform(const float* __restrict__ x,
    const float* __restrict__ w, const float* __restrict__ bias,
    float* __restrict__ Aout, float* __restrict__ Bvv, float* __restrict__ sqnp,
    unsigned int* __restrict__ xbu)
{
    __shared__ float w1m[64*64];
    __shared__ float w2t[64*64];
    __shared__ float xs[128*64];
    int t = threadIdx.x;
    int r0 = blockIdx.x * 128;
#pragma unroll
    for (int i = 0; i < 16; ++i) {
        int e = t + i*256; int f = e >> 6; int o = e & 63;
        float w2 = w[o*128 + 64 + f];
        float w1 = w[o*128 + f];
        w2t[f*64 + o] = w2;
        w1m[f*64 + o] = w1 - w2;
    }
#pragma unroll
    for (int i = 0; i < 32; ++i) { int idx = t + i*256; xs[idx] = x[(size_t)r0*64 + idx]; }
    __syncthreads();
    // bf16 copy: 128 rows x 32 uint pairs
#pragma unroll
    for (int i = 0; i < 16; ++i) {
        int e = t + i*256;
        xbu[(size_t)r0*32 + e] = pk2(xs[2*e], xs[2*e + 1]);
    }
    int o = t & 63;
    float br = bias[o];
    for (int g = 0; g < 32; ++g) {
        int rl = g*4 + (t >> 6);
        float a1 = 0.f, a2 = 0.f;
#pragma unroll
        for (int f = 0; f < 64; ++f) {
            float xv = xs[rl*64 + f];
            a1 += xv * w1m[f*64 + o];
            a2 += xv * w2t[f*64 + o];
        }
        int row = r0 + rl;
        Aout[(size_t)row*64 + o] = a1 + br;
        Bvv[(size_t)row*64 + o] = a2;
        if (o == 0) sqnp[row] = np_sq64(&xs[rl*64]);
    }
}

// Kernel 2: pipelined dbuf bf16 MFMA -> med3 flat-16 filter -> merge top-24 -> np-exact rescore -> top-16
__global__ __launch_bounds__(256, 4) void k_topk(const float4* __restrict__ x4,
    const uint4* __restrict__ xb, const float* __restrict__ sq, int* __restrict__ nbr)
{
    // phase1: bsh0 0..9216 | bsh1 9216..18432 | rsh 18432..27648 | sqc 27648..28160
    // phase2: cand 0..17408 | cand24 17408..20480
    __shared__ __align__(16) char smem[28160];
    unsigned short* bsh0 = (unsigned short*)smem;
    unsigned short* bsh1 = (unsigned short*)(smem + 9216);
    unsigned short* rsh  = (unsigned short*)(smem + 18432);
    float* sqc           = (float*)(smem + 27648);     // [2][64]
    unsigned int* cand   = (unsigned int*)smem;        // 64 rows x 68
    unsigned short* cand24 = (unsigned short*)(smem + 17408);

    int t = threadIdx.x;
    int lane = t & 63;
    int w = t >> 6;
    int ln = lane & 15, qd = lane >> 4;
    int batch = blockIdx.x >> 5;
    int strip = blockIdx.x & 31;
    int rbase = batch * NPERB;
    int r0g = rbase + strip * 64;

    // stage block's rows (bf16) + prefetch tile0
    {
        const uint4* src = xb + (size_t)r0g * 8;
#pragma unroll
        for (int i = 0; i < 2; ++i) {
            int l = t + i*256;
            uint4 v = src[l];
            *(uint4*)&rsh[(l >> 3)*72 + (l & 7)*8] = v;
        }
    }
    uint4 pf0, pf1; float sqpf;
    {
        const uint4* src = xb + (size_t)rbase * 8;
        pf0 = src[t]; pf1 = src[t + 256];
        sqpf = (t < 64) ? sq[rbase + t] : 0.f;
    }
    __syncthreads();
    bf16x8 rf0 = *(const bf16x8*)&rsh[(w*16 + ln)*72 + qd*8];
    bf16x8 rf1 = *(const bf16x8*)&rsh[(w*16 + ln)*72 + 32 + qd*8];
    float sqr16 = sq[r0g + w*16 + ln] + 16.f;

    // write tile0 -> bsh0, prefetch tile1
    *(uint4*)&bsh0[(t >> 3)*72 + (t & 7)*8] = pf0;
    { int l1 = t + 256; *(uint4*)&bsh0[(l1 >> 3)*72 + (l1 & 7)*8] = pf1; }
    if (t < 64) sqc[t] = sqpf;
    {
        const uint4* src = xb + ((size_t)rbase + 64) * 8;
        pf0 = src[t]; pf1 = src[t + 256];
        sqpf = (t < 64) ? sq[rbase + 64 + t] : 0.f;
    }
    __syncthreads();

    unsigned int ks[16];
#pragma unroll
    for (int j = 0; j < 16; ++j) ks[j] = 0xFFFFFFFFu;

    for (int ct = 0; ct < 32; ++ct) {
        unsigned short* bcur = (ct & 1) ? bsh1 : bsh0;
        const float* sqcur = sqc + (ct & 1)*64;
#pragma unroll
        for (int ct2 = 0; ct2 < 4; ++ct2) {
            int pt = ct2*16 + ln;
            bf16x8 a0 = *(const bf16x8*)&bcur[pt*72 + qd*8];
            bf16x8 a1 = *(const bf16x8*)&bcur[pt*72 + 32 + qd*8];
            f32x4 acc = {0.f, 0.f, 0.f, 0.f};
            acc = __builtin_amdgcn_mfma_f32_16x16x32_bf16(a0, rf0, acc, 0, 0, 0);
            acc = __builtin_amdgcn_mfma_f32_16x16x32_bf16(a1, rf1, acc, 0, 0, 0);
            f32x4 sc4 = *(const f32x4*)&sqcur[ct2*16 + qd*4];
            int idxb = ct*64 + ct2*16 + qd*4;
#pragma unroll
            for (int j = 0; j < 4; ++j) {
                float s = fmaf(-2.f, acc[j], sc4[j] + sqr16);   // > 0 always
                unsigned int u = (__float_as_uint(s) & 0xFFFFF800u) | (unsigned int)(idxb + j);
#pragma unroll
                for (int jj = 15; jj >= 1; --jj) ks[jj] = med3u(u, ks[jj-1], ks[jj]);
                ks[0] = min(ks[0], u);
            }
        }
        if (ct < 31) {
            unsigned short* bnext = (ct & 1) ? bsh0 : bsh1;   // holds tile ct-1: compute done
            *(uint4*)&bnext[(t >> 3)*72 + (t & 7)*8] = pf0;
            { int l1 = t + 256; *(uint4*)&bnext[(l1 >> 3)*72 + (l1 & 7)*8] = pf1; }
            if (t < 64) sqc[((ct + 1) & 1)*64 + t] = sqpf;
            if (ct < 30) {
                const uint4* src = xb + ((size_t)rbase + (ct + 2)*64) * 8;
                pf0 = src[t]; pf1 = src[t + 256];
                sqpf = (t < 64) ? sq[rbase + (ct + 2)*64 + t] : 0.f;
            }
        }
        __syncthreads();
    }

    // dump per-lane keys
    {
        int r = w*16 + ln;
#pragma unroll
        for (int j = 0; j < 16; ++j) cand[r*68 + qd*16 + j] = ks[j];
    }
    __syncthreads();

    // merge to bf16-top-24 per row
    if (t < 64) {
        unsigned int m24[NCAND];
#pragma unroll
        for (int j = 0; j < NCAND; ++j) m24[j] = 0xFFFFFFFFu;
        for (int i = 0; i < 64; ++i) {
            unsigned int u = cand[t*68 + i];
#pragma unroll
            for (int jj = NCAND-1; jj >= 1; --jj) m24[jj] = med3u(u, m24[jj-1], m24[jj]);
            m24[0] = min(m24[0], u);
        }
#pragma unroll
        for (int j = 0; j < NCAND; ++j) cand24[t*NCAND + j] = (unsigned short)(m24[j] & 0x7FFu);
    }
    __syncthreads();

    // np-exact rescore (R6-verified chain): 4 groups x 6 candidates per row
    {
        int r = t & 63, grp = t >> 6;
        float sqr = sq[r0g + r];
        float4 xrA[8];
#pragma unroll
        for (int i = 0; i < 8; ++i) xrA[i] = x4[(size_t)(r0g + r)*16 + i];
        float* kdf = (float*)cand;
#pragma unroll
        for (int m6 = 0; m6 < 6; ++m6) {
            int m = grp*6 + m6;
            int c = (int)cand24[r*NCAND + m];
            const float4* xb4 = &x4[(size_t)(rbase + c)*16];
            float dot = 0.f;
#pragma unroll
            for (int i = 0; i < 8; ++i) {
                float4 a = xrA[i]; float4 b = xb4[i];
                dot = fmaf(a.x, b.x, dot); dot = fmaf(a.y, b.y, dot);
                dot = fmaf(a.z, b.z, dot); dot = fmaf(a.w, b.w, dot);
            }
#pragma unroll
            for (int i = 8; i < 16; ++i) {
                float4 a = x4[(size_t)(r0g + r)*16 + i]; float4 b = xb4[i];
                dot = fmaf(a.x, b.x, dot); dot = fmaf(a.y, b.y, dot);
                dot = fmaf(a.z, b.z, dot); dot = fmaf(a.w, b.w, dot);
            }
            float kd = __fsub_rn(__fadd_rn(sqr, sq[rbase + c]), __fmul_rn(2.0f, dot));
            kdf[r*68 + m] = kd;
            cand[r*68 + 32 + m] = (unsigned int)c;
        }
    }
    __syncthreads();

    // exact top-16 with (key, idx) ordering
    if (t < 64) {
        float* kdf = (float*)cand;
        float dk[KNN]; int di[KNN];
#pragma unroll
        for (int j = 0; j < KNN; ++j) { dk[j] = FLT_MAX; di[j] = 0x7fffffff; }
        for (int m = 0; m < NCAND; ++m) {
            float kd = kdf[t*68 + m];
            int c = (int)cand[t*68 + 32 + m];
            bool better = (kd < dk[KNN-1]) || (kd == dk[KNN-1] && c < di[KNN-1]);
            if (better) {
#pragma unroll
                for (int j = KNN-1; j >= 1; --j) {
                    bool sh = (dk[j-1] > kd) || (dk[j-1] == kd && di[j-1] > c);
                    bool pl = (!sh) && ((dk[j] > kd) || (dk[j] == kd && di[j] > c));
                    float nk = sh ? dk[j-1] : (pl ? kd : dk[j]);
                    int ni = sh ? di[j-1] : (pl ? c : di[j]);
                    dk[j] = nk; di[j] = ni;
                }
                if ((dk[0] > kd) || (dk[0] == kd && di[0] > c)) { dk[0] = kd; di[0] = c; }
            }
        }
#pragma unroll
        for (int k = 0; k < KNN; ++k) nbr[(size_t)(r0g + t)*16 + k] = di[k];
    }
}

// Kernel 3: out[n,o] = relu(out[n,o] + max_k Bv[nbr_k, o])   (out holds A from k1)
__global__ __launch_bounds__(256) void k_combine(const float* __restrict__ Bvv,
    const int* __restrict__ nbr, float* __restrict__ out)
{
    int t = threadIdx.x;
    int row = blockIdx.x*4 + (t >> 6);
    int o = t & 63;
    int rb = (row >> 11) << 11;
    float m = -FLT_MAX;
#pragma unroll
    for (int k = 0; k < 16; ++k) {
        int c = nbr[(size_t)row*16 + k];
        m = fmaxf(m, Bvv[(size_t)(rb + c)*64 + o]);
    }
    out[(size_t)row*64 + o] = fmaxf(out[(size_t)row*64 + o] + m, 0.f);
}

extern "C" void kernel_launch(void* const* d_in, const int* in_sizes, int n_in,
                              void* d_out, int out_size, void* d_ws, size_t ws_size,
                              hipStream_t stream) {
    const float* x    = (const float*)d_in[0];
    // d_in[1] = batch (contiguous per batch; unused)
    const float* w    = (const float*)d_in[2];
    const float* bias = (const float*)d_in[3];
    float* out = (float*)d_out;

    float* Bvv  = (float*)d_ws;                       // 32 MB
    float* sqnp = Bvv + (size_t)NTOT * 64;            // 0.5 MB
    int*   nbr  = (int*)(sqnp + NTOT);                // 8 MB
    unsigned int* xbu = (unsigned int*)(nbr + (size_t)NTOT * 16);   // 16 MB bf16 x

    k_transform<<<1024, 256, 0, stream>>>(x, w, bias, out, Bvv, sqnp, xbu);
    k_topk<<<2048, 256, 0, stream>>>((const float4*)x, (const uint4*)xbu, sqnp, nbr);
    k_combine<<<NTOT/4, 256, 0, stream>>>(Bvv, nbr, out);
}